// Round 2
// baseline (3726.946 us; speedup 1.0000x reference)
//
#include <hip/hip_runtime.h>
#include <hip/hip_bf16.h>

// ---------------- workspace layout (float-element offsets) ----------------
#define S_MAX 32
#define VST   2052                    // per-s vector stride (covers nt+1 <= 2048)
#define YSLOT (VST * S_MAX)           // 65664 floats per y iteration slot
#define KSLOT 1057824                 // bf16 elems per s slot >= max (nt+1)*ldp (1,057,812)

#define OFF_MAX  64                   // 32 uints (float bits, atomicMax of M)
#define OFF_SUM  96                   // 32 floats (atomicAdd of sum M)
#define OFF_IT   128                  // int[2048] treated indices
#define OFF_IC   2176                 // int[2048] control indices
#define OFF_NORM 4352                 // float[32][2048] row sq-norms -> ends 69888
#define OFF_U    69888                // float[32][VST] current u vector -> ends 135552
#define OFF_Y    135552               // 21 slots x YSLOT (atomic accum, pre-zeroed) -> ends 1514496
#define OFF_KF   1514496              // bf16 K region start (float offset); 32*KSLOT bf16 = 67.7 MB
// total ws usage: 1514496*4 + 32*KSLOT*2 = 73,758,720 bytes (~70.3 MiB)

__device__ __forceinline__ float bf2f(unsigned short u) {
    return __uint_as_float(((unsigned)u) << 16);
}
__device__ __forceinline__ unsigned short f2bf(float f) {
    __hip_bfloat16 h = __float2bfloat16(f);
    return *reinterpret_cast<unsigned short*>(&h);
}

// ---------------------------------------------------------------------------
// 1) index compaction + meta + u0 = a  (one block)
__global__ __launch_bounds__(1024) void idx_kernel(const int* __restrict__ t, float* __restrict__ ws) {
    __shared__ int sc[2048];
    const int tid = threadIdx.x;
    int p0 = (t[tid] > 0) ? 1 : 0;
    int p1 = (t[tid + 1024] > 0) ? 1 : 0;
    sc[tid] = p0; sc[tid + 1024] = p1;
    __syncthreads();
    for (int off = 1; off < 2048; off <<= 1) {
        int v0 = 0, v1 = 0;
        if (tid >= off)        v0 = sc[tid - off];
        if (tid + 1024 >= off) v1 = sc[tid + 1024 - off];
        __syncthreads();
        sc[tid] += v0; sc[tid + 1024] += v1;
        __syncthreads();
    }
    const int incl0 = sc[tid], incl1 = sc[tid + 1024];
    const int nt = sc[2047];
    const int nc = 2048 - nt;
    int* itl = (int*)(ws + OFF_IT);
    int* icl = (int*)(ws + OFF_IC);
    if (p0) itl[incl0 - 1] = tid;        else icl[tid - incl0] = tid;
    if (p1) itl[incl1 - 1] = tid + 1024; else icl[tid + 1024 - incl1] = tid + 1024;

    const float p = (float)nt / 2048.0f;
    const float a_main = p / (float)nt;
    const float a_last = 1.0f - p;
    if (tid == 0) {
        ((int*)ws)[0] = nt;
        ((int*)ws)[1] = nc;
        ws[2] = p;
        ws[3] = a_main;
        ws[4] = a_last;
        ws[5] = (1.0f - p) / (float)nc;   // b_main
        ws[6] = p;                        // b_last
    }
    // u0 = a (indices 0..nt), 0 beyond
    for (int s = 0; s < S_MAX; s++) {
        float* u = ws + OFF_U + s * VST;
        for (int i = tid; i < VST; i += 1024)
            u[i] = (i < nt) ? a_main : ((i == nt) ? a_last : 0.0f);
    }
}

// ---------------------------------------------------------------------------
// 2) row squared norms: one wave per (n,s) row of 256 floats
__global__ __launch_bounds__(256) void norm_kernel(const float* __restrict__ enc, float* __restrict__ ws) {
    const int gw = blockIdx.x * 4 + (threadIdx.x >> 6);   // 0..65535
    const int lane = threadIdx.x & 63;
    const int n = gw >> 5, s = gw & 31;
    const float4* row = (const float4*)(enc + ((size_t)n * 32 + s) * 256);
    float4 v = row[lane];
    float ss = v.x * v.x + v.y * v.y + v.z * v.z + v.w * v.w;
    for (int off = 32; off; off >>= 1) ss += __shfl_xor(ss, off);
    if (lane == 0) ws[OFF_NORM + s * 2048 + n] = ss;
}

// ---------------------------------------------------------------------------
// 3) M tiles (f32 GEMM, 64x64/block, 4x4/thread) -> bf16 M + f32 max/sum stats
__global__ __launch_bounds__(256) void m_kernel(const float* __restrict__ enc, float* __restrict__ ws) {
    const int s = blockIdx.z;
    const int nt = ((const int*)ws)[0], nc = ((const int*)ws)[1];
    const int ibase = blockIdx.y * 64, jbase = blockIdx.x * 64;
    if (ibase >= nt || jbase >= nc) return;
    const int ldp = ((nc + 1) + 7) & ~7;

    __shared__ float A[32][68];
    __shared__ float B[32][68];
    __shared__ int   ridx[64], cidx[64];
    __shared__ float nrmA[64], nrmB[64];
    __shared__ float rmax[4], rsum[4];

    const int tid = threadIdx.x;
    const int* itl = (const int*)(ws + OFF_IT);
    const int* icl = (const int*)(ws + OFF_IC);
    if (tid < 64) {
        int i = ibase + tid;
        int g = itl[(i < nt) ? i : (nt - 1)];
        ridx[tid] = g;
        nrmA[tid] = ws[OFF_NORM + s * 2048 + g];
    } else if (tid < 128) {
        int j = jbase + (tid - 64);
        int g = icl[(j < nc) ? j : (nc - 1)];
        cidx[tid - 64] = g;
        nrmB[tid - 64] = ws[OFF_NORM + s * 2048 + g];
    }
    __syncthreads();

    const int tr = tid & 15, tc = tid >> 4;
    const int lr = tid >> 2, lq = tid & 3;
    float acc[4][4] = {};

    for (int d0 = 0; d0 < 256; d0 += 32) {
        const float* pa = enc + ((size_t)ridx[lr] * 32 + s) * 256 + d0 + lq * 8;
        const float* pb = enc + ((size_t)cidx[lr] * 32 + s) * 256 + d0 + lq * 8;
        float4 a0 = *(const float4*)pa, a1 = *(const float4*)(pa + 4);
        float4 b0 = *(const float4*)pb, b1 = *(const float4*)(pb + 4);
        __syncthreads();
        int dd = lq * 8;
        A[dd+0][lr]=a0.x; A[dd+1][lr]=a0.y; A[dd+2][lr]=a0.z; A[dd+3][lr]=a0.w;
        A[dd+4][lr]=a1.x; A[dd+5][lr]=a1.y; A[dd+6][lr]=a1.z; A[dd+7][lr]=a1.w;
        B[dd+0][lr]=b0.x; B[dd+1][lr]=b0.y; B[dd+2][lr]=b0.z; B[dd+3][lr]=b0.w;
        B[dd+4][lr]=b1.x; B[dd+5][lr]=b1.y; B[dd+6][lr]=b1.z; B[dd+7][lr]=b1.w;
        __syncthreads();
        #pragma unroll
        for (int dd2 = 0; dd2 < 32; dd2++) {
            float4 av = *(const float4*)&A[dd2][tr * 4];
            float4 bv = *(const float4*)&B[dd2][tc * 4];
            acc[0][0] += av.x*bv.x; acc[0][1] += av.x*bv.y; acc[0][2] += av.x*bv.z; acc[0][3] += av.x*bv.w;
            acc[1][0] += av.y*bv.x; acc[1][1] += av.y*bv.y; acc[1][2] += av.y*bv.z; acc[1][3] += av.y*bv.w;
            acc[2][0] += av.z*bv.x; acc[2][1] += av.z*bv.y; acc[2][2] += av.z*bv.z; acc[2][3] += av.z*bv.w;
            acc[3][0] += av.w*bv.x; acc[3][1] += av.w*bv.y; acc[3][2] += av.w*bv.z; acc[3][3] += av.w*bv.w;
        }
    }

    unsigned short* Ks = reinterpret_cast<unsigned short*>(ws + OFF_KF) + (size_t)s * KSLOT;
    float lmax = 0.0f, lsum = 0.0f;
    #pragma unroll
    for (int ii = 0; ii < 4; ii++) {
        const int i = ibase + tr * 4 + ii;
        if (i >= nt) continue;
        float mv[4];
        int jb4 = jbase + tc * 4;
        #pragma unroll
        for (int jj = 0; jj < 4; jj++) {
            float m = nrmA[tr * 4 + ii] + nrmB[tc * 4 + jj] - 2.0f * acc[ii][jj];
            mv[jj] = m;
            if (jb4 + jj < nc) { lmax = fmaxf(lmax, m); lsum += m; }
        }
        if (jb4 + 3 < nc) {
            ushort4 pk = { f2bf(mv[0]), f2bf(mv[1]), f2bf(mv[2]), f2bf(mv[3]) };
            *reinterpret_cast<ushort4*>(Ks + (size_t)i * ldp + jb4) = pk;   // 8B aligned (ldp%8==0, jb4%4==0)
        } else {
            for (int jj = 0; jj < 4; jj++)
                if (jb4 + jj < nc) Ks[(size_t)i * ldp + jb4 + jj] = f2bf(mv[jj]);
        }
    }
    for (int off = 32; off; off >>= 1) {
        lmax = fmaxf(lmax, __shfl_xor(lmax, off));
        lsum += __shfl_xor(lsum, off);
    }
    if ((tid & 63) == 0) { rmax[tid >> 6] = lmax; rsum[tid >> 6] = lsum; }
    __syncthreads();
    if (tid == 0) {
        float bm = fmaxf(fmaxf(rmax[0], rmax[1]), fmaxf(rmax[2], rmax[3]));
        float bs = rsum[0] + rsum[1] + rsum[2] + rsum[3];
        atomicMax(&((unsigned int*)ws)[OFF_MAX + s], __float_as_uint(bm));
        atomicAdd(&ws[OFF_SUM + s], bs);
    }
}

// ---------------------------------------------------------------------------
// 4) K = exp(-lam*Mt)+1e-6 in place (bf16), delta pad row/col, zero ldp tail
__global__ __launch_bounds__(256) void k_kernel(float* __restrict__ ws) {
    const int i = blockIdx.x, s = blockIdx.y;
    const int nt = ((const int*)ws)[0], nc = ((const int*)ws)[1];
    if (i > nt) return;
    const int ldp = ((nc + 1) + 7) & ~7;
    const float delta = __uint_as_float(((const unsigned int*)ws)[OFF_MAX + s]);
    const float lam = (float)nt * (float)nc / ws[OFF_SUM + s];
    const float kpad = __expf(-lam * delta) + 1e-6f;
    unsigned short* row = reinterpret_cast<unsigned short*>(ws + OFF_KF) + (size_t)s * KSLOT + (size_t)i * ldp;
    for (int j = threadIdx.x; j < ldp; j += 256) {
        float kv;
        if (j > nc)                    kv = 0.0f;                 // padded tail: never contributes
        else if (i < nt && j < nc)     kv = __expf(-lam * bf2f(row[j])) + 1e-6f;
        else if (i == nt && j == nc)   kv = 1.0f + 1e-6f;         // corner Mt=0
        else                           kv = kpad;                 // delta pad row/col
        row[j] = f2bf(kv);
    }
}

// ---------------------------------------------------------------------------
// 5a) phase A: y[k] += K^T u  (atomic over i-chunks; y pre-zeroed slots)
__global__ __launch_bounds__(256) void phaseA_kernel(float* __restrict__ ws, int k) {
    const int s = blockIdx.z;
    const int nt = ((const int*)ws)[0], nc = ((const int*)ws)[1];
    const int jb = blockIdx.x * 512, ib = blockIdx.y * 256;
    if (jb > nc || ib > nt) return;
    const int ldp = ((nc + 1) + 7) & ~7;
    const float* u = ws + OFF_U + s * VST;
    float*       y = ws + OFF_Y + (size_t)k * YSLOT + s * VST;

    __shared__ float u_l[256];
    const int tid = threadIdx.x;
    const int rend = min(256, nt + 1 - ib);
    u_l[tid] = (tid < rend) ? u[ib + tid] : 0.0f;
    __syncthreads();

    const unsigned short* Kbase = reinterpret_cast<const unsigned short*>(ws + OFF_KF) + (size_t)s * KSLOT;
    const int j0 = jb + tid, j1 = jb + 256 + tid;
    const bool m0 = (j0 <= nc), m1 = (j1 <= nc);
    if (!m0) return;
    float a0 = 0.0f, a1 = 0.0f;
    const unsigned short* Kp = Kbase + (size_t)ib * ldp;
    #pragma unroll 4
    for (int r = 0; r < rend; r++) {
        const unsigned short* Kr = Kp + (size_t)r * ldp;
        float uv = u_l[r];
        a0 += bf2f(Kr[j0]) * uv;
        if (m1) a1 += bf2f(Kr[j1]) * uv;
    }
    atomicAdd(&y[j0], a0);
    if (m1) atomicAdd(&y[j1], a1);
}

// ---------------------------------------------------------------------------
// 5b) phase B: u = a / (K (b/y[k]))  — whole row per wave, no atomics
__global__ __launch_bounds__(256) void phaseB_kernel(float* __restrict__ ws, int k) {
    const int s = blockIdx.y;
    const int nt = ((const int*)ws)[0], nc = ((const int*)ws)[1];
    const int rb = blockIdx.x * 128;
    if (rb > nt) return;
    const int ldp = ((nc + 1) + 7) & ~7;
    const float b_main = ws[5], b_last = ws[6];
    const float* y = ws + OFF_Y + (size_t)k * YSLOT + s * VST;
    float*       u = ws + OFF_U + s * VST;
    const float a_main = ws[3], a_last = ws[4];

    __shared__ __align__(16) float w_l[2056];
    const int tid = threadIdx.x, lane = tid & 63, wave = tid >> 6;
    for (int j = tid; j < 2056; j += 256)
        w_l[j] = (j <= nc) ? (((j < nc) ? b_main : b_last) / y[j]) : 0.0f;
    __syncthreads();

    const unsigned short* Kbase = reinterpret_cast<const unsigned short*>(ws + OFF_KF) + (size_t)s * KSLOT;
    for (int rr = wave; rr < 128; rr += 4) {
        const int i = rb + rr;
        if (i > nt) break;
        const unsigned short* Krow = Kbase + (size_t)i * ldp;
        float acc = 0.0f;
        for (int j4 = 4 * lane; j4 < ldp; j4 += 256) {
            ushort4 kk = *reinterpret_cast<const ushort4*>(Krow + j4);   // 8B aligned
            float4 wv = *reinterpret_cast<const float4*>(&w_l[j4]);
            acc += bf2f(kk.x) * wv.x + bf2f(kk.y) * wv.y + bf2f(kk.z) * wv.z + bf2f(kk.w) * wv.w;
        }
        for (int off = 32; off; off >>= 1) acc += __shfl_xor(acc, off);
        if (lane == 0) u[i] = ((i < nt) ? a_main : a_last) / acc;
    }
}

// ---------------------------------------------------------------------------
// 6) value: out += 2 * sum_ij u_i K_ij Mt_ij v_j  (Mt via log recovery)
__global__ __launch_bounds__(256) void value_kernel(float* __restrict__ ws, const int* __restrict__ seqlen,
                                                    float* __restrict__ out) {
    const int s = blockIdx.y;
    if (s >= *seqlen) return;
    const int nt = ((const int*)ws)[0], nc = ((const int*)ws)[1];
    const int rb = blockIdx.x * 128;
    if (rb > nt) return;
    const int ldp = ((nc + 1) + 7) & ~7;
    const float b_main = ws[5], b_last = ws[6];
    const float a_main = ws[3], a_last = ws[4];
    const float meanM = ws[OFF_SUM + s] / ((float)nt * (float)nc);   // 1/lam
    const float* y20 = ws + OFF_Y + (size_t)20 * YSLOT + s * VST;
    const float* u   = ws + OFF_U + s * VST;

    __shared__ __align__(16) float v_l[2056];
    __shared__ float wtot[4];
    const int tid = threadIdx.x, lane = tid & 63, wave = tid >> 6;
    for (int j = tid; j < 2056; j += 256)
        v_l[j] = (j <= nc) ? (((j < nc) ? b_main : b_last) / y20[j]) : 0.0f;
    __syncthreads();

    const unsigned short* Kbase = reinterpret_cast<const unsigned short*>(ws + OFF_KF) + (size_t)s * KSLOT;
    float wsum = 0.0f;
    for (int rr = wave; rr < 128; rr += 4) {
        const int i = rb + rr;
        if (i > nt) break;
        const unsigned short* Krow = Kbase + (size_t)i * ldp;
        float acc = 0.0f;
        for (int j4 = 4 * lane; j4 < ldp; j4 += 256) {
            ushort4 kk = *reinterpret_cast<const ushort4*>(Krow + j4);
            float4 vv = *reinterpret_cast<const float4*>(&v_l[j4]);
            float k0 = bf2f(kk.x), k1 = bf2f(kk.y), k2 = bf2f(kk.z), k3 = bf2f(kk.w);
            float m0 = -__logf(fmaxf(k0 - 1e-6f, 1e-30f)) * meanM;
            float m1 = -__logf(fmaxf(k1 - 1e-6f, 1e-30f)) * meanM;
            float m2 = -__logf(fmaxf(k2 - 1e-6f, 1e-30f)) * meanM;
            float m3 = -__logf(fmaxf(k3 - 1e-6f, 1e-30f)) * meanM;
            acc += k0 * m0 * vv.x + k1 * m1 * vv.y + k2 * m2 * vv.z + k3 * m3 * vv.w;
        }
        for (int off = 32; off; off >>= 1) acc += __shfl_xor(acc, off);
        float ui = ((i < nt) ? a_main : a_last) / 1.0f;  // placeholder, replaced below
        ui = u[i];
        wsum += ui * acc;
    }
    if (lane == 0) wtot[wave] = wsum;
    __syncthreads();
    if (tid == 0) atomicAdd(out, 2.0f * (wtot[0] + wtot[1] + wtot[2] + wtot[3]));
}

// ---------------------------------------------------------------------------
extern "C" void kernel_launch(void* const* d_in, const int* in_sizes, int n_in,
                              void* d_out, int out_size, void* d_ws, size_t ws_size,
                              hipStream_t stream) {
    const float* enc  = (const float*)d_in[0];
    const int* seqlen = (const int*)d_in[1];
    const int* t      = (const int*)d_in[2];
    float* out = (float*)d_out;
    float* ws  = (float*)d_ws;

    hipMemsetAsync(d_out, 0, sizeof(float), stream);
    hipMemsetAsync(d_ws, 0, (size_t)(OFF_Y + 21 * YSLOT) * sizeof(float), stream);  // 6.06 MB base region

    idx_kernel <<<1, 1024, 0, stream>>>(t, ws);
    norm_kernel<<<16384, 256, 0, stream>>>(enc, ws);
    m_kernel   <<<dim3(32, 32, 32), 256, 0, stream>>>(enc, ws);
    k_kernel   <<<dim3(2048, 32), 256, 0, stream>>>(ws);

    for (int k = 0; k < 20; k++) {
        phaseA_kernel<<<dim3(4, 8, 32), 256, 0, stream>>>(ws, k);
        phaseB_kernel<<<dim3(16, 32),   256, 0, stream>>>(ws, k);
    }
    phaseA_kernel<<<dim3(4, 8, 32), 256, 0, stream>>>(ws, 20);
    value_kernel <<<dim3(16, 32),   256, 0, stream>>>(ws, seqlen, out);
}